// Round 7
// baseline (50.680 us; speedup 1.0000x reference)
//
#include <hip/hip_runtime.h>
#include <math.h>

#define BATCH 32
#define ND 512
#define NC 100
#define NT 256          // 4 waves per block
#define BIGNEG 1000000.0f

// tile bases: 0,32,64,68 (last overlaps 64..95 -> every slot live, max is idempotent)
__device__ __forceinline__ int tbase(int h) { return (h < 3) ? h * 32 : 68; }

__global__ __launch_bounds__(NT, 4) void adv_main(
    const float* __restrict__ z, const float* __restrict__ wu,
    const float* __restrict__ wl, float* __restrict__ wsS)
{
  // 512 blocks = 32 b x 16 tiles; XCD-chunk swizzle (512 = 8*64, bijective)
  int id = (blockIdx.x & 7) * 64 + (blockIdx.x >> 3);
  const int b    = id >> 4;
  const int tile = id & 15;
  const int ibase = tbase(tile >> 2);
  const int jbase = tbase(tile & 3);

  const int tid = threadIdx.x;
  const int w   = tid >> 6;          // wave: n in [w*128, w*128+128)
  const int l   = tid & 63;
  const int io  = l >> 3, jo = l & 7;

  __shared__ __align__(16) float s_w[ND];       // width_n = hi-lo (0.5 deferred)
  __shared__ float s_red[3][64][17];            // acc dumps, stride 17 (conflict-free)

  // stage widths
  {
    const float* zb = z + b * 2 * ND;
    for (int n = tid; n < ND; n += NT) s_w[n] = zb[ND + n] - zb[n];
  }
  __syncthreads();

  float acc[4][4] = {{0.f,0.f,0.f,0.f},{0.f,0.f,0.f,0.f},
                     {0.f,0.f,0.f,0.f},{0.f,0.f,0.f,0.f}};

  const int n0 = w * 128;
  const float* pu = wu + ((size_t)b * ND + n0) * NC + ibase + (io << 2);
  const float* pl = wl + ((size_t)b * ND + n0) * NC + jbase + (jo << 2);
  const float4* wp = (const float4*)(s_w + n0);

  for (int t4 = 0; t4 < 32; ++t4) {
    float4 wd = wp[t4];                        // broadcast ds_read_b128, 1 per 4 n
    float wda[4] = {wd.x, wd.y, wd.z, wd.w};
#pragma unroll
    for (int u = 0; u < 4; ++u) {
      const int t = t4 * 4 + u;
      float4 U = *(const float4*)(pu + (size_t)t * NC);   // 2-line gather, L1/L2
      float4 V = *(const float4*)(pl + (size_t)t * NC);
      float uu[4] = {U.x, U.y, U.z, U.w};
      float vv[4] = {V.x, V.y, V.z, V.w};
      float wn = wda[u];
#pragma unroll
      for (int k = 0; k < 4; ++k)
#pragma unroll
        for (int m2 = 0; m2 < 4; ++m2)
          acc[k][m2] = fmaf(wn, fabsf(uu[k] - vv[m2]), acc[k][m2]);
    }
  }

  // cross-wave n-sum: waves 1..3 dump, wave 0 combines and stores the 32x32 tile
  if (w > 0) {
    float* pr = &s_red[w - 1][l][0];
#pragma unroll
    for (int k = 0; k < 4; ++k)
#pragma unroll
      for (int m2 = 0; m2 < 4; ++m2) pr[k * 4 + m2] = acc[k][m2];
  }
  __syncthreads();
  if (w == 0) {
    float* base = wsS + ((size_t)(b * 16 + tile) << 10);
#pragma unroll
    for (int k = 0; k < 4; ++k) {
      float4 o;
      float* op = (float*)&o;
#pragma unroll
      for (int m2 = 0; m2 < 4; ++m2)
        op[m2] = acc[k][m2] + s_red[0][l][k*4+m2] + s_red[1][l][k*4+m2] + s_red[2][l][k*4+m2];
      *(float4*)(base + (((io << 2) + k) << 5) + (jo << 2)) = o;  // coalesced
    }
  }
}

__global__ __launch_bounds__(NT) void adv_reduce(
    const float* __restrict__ z, const float* __restrict__ wu,
    const float* __restrict__ wl, const float* __restrict__ bu,
    const float* __restrict__ bl, const float* __restrict__ y,
    const float* __restrict__ wsS, float* __restrict__ out)
{
  const int b = blockIdx.x;
  const int t = threadIdx.x;
  __shared__ float s_c[ND];
  __shared__ float s_ai[128];   //  accc_i + bu_i - BIG*y_i
  __shared__ float s_aj[128];   // -L_j - bl_j - BIG*(1-y_j)
  __shared__ float s_mx[4];

  const float* zb = z + b * 2 * ND;
  for (int n = t; n < ND; n += NT) s_c[n] = 0.5f * (zb[n] + zb[ND + n]);
  __syncthreads();

  // separable linear terms: waves 0-1 -> accc_i from wu; waves 2-3 -> L_j from wl
  if (t < 128) {
    const int i = (t < NC) ? t : NC - 1;
    const float* p = wu + (size_t)b * ND * NC + i;
    float s = 0.f;
#pragma unroll 8
    for (int n = 0; n < ND; ++n) s = fmaf(s_c[n], p[(size_t)n * NC], s);
    s_ai[t] = s + bu[b * NC + i] - BIGNEG * y[b * NC + i];
  } else {
    const int j = t - 128;
    const int jc = (j < NC) ? j : NC - 1;
    const float* p = wl + (size_t)b * ND * NC + jc;
    float s = 0.f;
#pragma unroll 8
    for (int n = 0; n < ND; ++n) s = fmaf(s_c[n], p[(size_t)n * NC], s);
    s_aj[j] = -s - bl[b * NC + jc] - BIGNEG * (1.0f - y[b * NC + jc]);
  }
  __syncthreads();

  // bias + 0.5*S, max over all 16 tiles (16384 slots / 256 threads = 64 each)
  float m = -INFINITY;
  const float* S = wsS + ((size_t)b << 14);
#pragma unroll 8
  for (int k = 0; k < 64; ++k) {
    const int f = t + (k << 8);
    const int tl = f >> 10, rem = f & 1023;
    const int i = tbase(tl >> 2) + (rem >> 5);
    const int j = tbase(tl & 3) + (rem & 31);
    m = fmaxf(m, 0.5f * S[f] + s_ai[i] + s_aj[j]);
  }
#pragma unroll
  for (int off = 32; off; off >>= 1) m = fmaxf(m, __shfl_down(m, off, 64));
  if ((t & 63) == 0) s_mx[t >> 6] = m;
  __syncthreads();
  if (t == 0)
    out[b] = fmaxf(fmaxf(s_mx[0], s_mx[1]), fmaxf(s_mx[2], s_mx[3]));
}

extern "C" void kernel_launch(void* const* d_in, const int* in_sizes, int n_in,
                              void* d_out, int out_size, void* d_ws, size_t ws_size,
                              hipStream_t stream) {
  // inputs: 0:x (unused), 1:z_tensor, 2:w_u, 3:b_u, 4:w_l, 5:b_l, 6:y_tensor
  const float* z  = (const float*)d_in[1];
  const float* wu = (const float*)d_in[2];
  const float* bu = (const float*)d_in[3];
  const float* wl = (const float*)d_in[4];
  const float* bl = (const float*)d_in[5];
  const float* y  = (const float*)d_in[6];
  float* wsS = (float*)d_ws;   // 32*16*1024 floats = 2 MB

  adv_main<<<512, NT, 0, stream>>>(z, wu, wl, wsS);
  adv_reduce<<<BATCH, NT, 0, stream>>>(z, wu, wl, bu, bl, y, wsS, (float*)d_out);
}

// Round 8
// 48.877 us; speedup vs baseline: 1.0369x; 1.0369x over previous
//
#include <hip/hip_runtime.h>
#include <math.h>

#define BATCH 32
#define ND 512
#define NC 100
#define NT 256
#define NIP 25          // i-passes of 4 -> i exactly 0..99
#define NSPL 4          // n split: 128 n per block, 32 per wave
#define NGRID (BATCH*NIP*NSPL)   // 3200
#define BIGNEG 1000000.0f

__global__ __launch_bounds__(NT, 6) void adv_main(
    const float* __restrict__ z, const float* __restrict__ wu,
    const float* __restrict__ wl, float* __restrict__ P)
{
  // XCD-chunk swizzle (3200 = 8*400, bijective)
  int id = (blockIdx.x & 7) * (NGRID / 8) + (blockIdx.x >> 3);
  const int b  = id / (NIP * NSPL);
  const int rm = id - b * (NIP * NSPL);
  const int ip = rm >> 2;
  const int s  = rm & 3;
  const int i0 = ip << 2;

  const int tid = threadIdx.x;
  const int w = tid >> 6, l = tid & 63;
  const int jl = (2 * l < 98) ? 2 * l : 98;   // clamp: slots j>=100 dup j=98/99 (masked in fin)

  __shared__ float s_red[3][64][10];   // stride 10 words -> 2-way banks (free)

  const int n0 = s * (ND / NSPL) + w * 32;    // 32 n per wave
  const float* up = wu + ((size_t)b * ND + n0) * NC + i0;   // uniform -> s_load
  const float* vp = wl + ((size_t)b * ND + n0) * NC + jl;   // per-lane, coalesced b64
  const float* zl = z + (size_t)b * 2 * ND + n0;            // uniform -> s_load

  float a00=0.f,a01=0.f,a10=0.f,a11=0.f,a20=0.f,a21=0.f,a30=0.f,a31=0.f;

#pragma unroll 2
  for (int g = 0; g < 8; ++g) {
#pragma unroll
    for (int k = 0; k < 4; ++k) {
      const int n = g * 4 + k;
      float lo = zl[n], hi = zl[ND + n];
      float cc = hi + lo, rr = hi - lo;           // 2c, 2r (0.5 applied in fin)
      float4 u = *(const float4*)(up + (size_t)n * NC);
      float2 v = *(const float2*)(vp + (size_t)n * NC);
      float d;
      d = u.x - v.x; a00 = fmaf(cc, d, fmaf(rr, fabsf(d), a00));
      d = u.x - v.y; a01 = fmaf(cc, d, fmaf(rr, fabsf(d), a01));
      d = u.y - v.x; a10 = fmaf(cc, d, fmaf(rr, fabsf(d), a10));
      d = u.y - v.y; a11 = fmaf(cc, d, fmaf(rr, fabsf(d), a11));
      d = u.z - v.x; a20 = fmaf(cc, d, fmaf(rr, fabsf(d), a20));
      d = u.z - v.y; a21 = fmaf(cc, d, fmaf(rr, fabsf(d), a21));
      d = u.w - v.x; a30 = fmaf(cc, d, fmaf(rr, fabsf(d), a30));
      d = u.w - v.y; a31 = fmaf(cc, d, fmaf(rr, fabsf(d), a31));
    }
  }

  // cross-wave n-sum (4 waves -> 1 tile)
  if (w > 0) {
    float* pr = &s_red[w - 1][l][0];
    pr[0]=a00; pr[1]=a01; pr[2]=a10; pr[3]=a11;
    pr[4]=a20; pr[5]=a21; pr[6]=a30; pr[7]=a31;
  }
  __syncthreads();
  if (w == 0) {
#pragma unroll
    for (int q = 0; q < 3; ++q) {
      const float* pr = &s_red[q][l][0];
      a00+=pr[0]; a01+=pr[1]; a10+=pr[2]; a11+=pr[3];
      a20+=pr[4]; a21+=pr[5]; a30+=pr[6]; a31+=pr[7];
    }
    float* base = P + (size_t)((b * NIP + ip) * NSPL + s) * 512;
    *(float2*)(base + 0 * 128 + 2 * l) = make_float2(a00, a01);
    *(float2*)(base + 1 * 128 + 2 * l) = make_float2(a10, a11);
    *(float2*)(base + 2 * 128 + 2 * l) = make_float2(a20, a21);
    *(float2*)(base + 3 * 128 + 2 * l) = make_float2(a30, a31);
  }
}

__global__ __launch_bounds__(128) void adv_fin(
    const float* __restrict__ P, const float* __restrict__ bu,
    const float* __restrict__ bl, const float* __restrict__ y,
    float* __restrict__ out)
{
  const int b = blockIdx.x, t = threadIdx.x;
  __shared__ float s_row[NC];
  __shared__ float s_mx[2];
  if (t < NC) s_row[t] = bu[b * NC + t] - BIGNEG * y[b * NC + t];
  __syncthreads();

  float m = -INFINITY;
  if (t < NC) {
    const float colt = -bl[b * NC + t] - BIGNEG * (1.0f - y[b * NC + t]);
    for (int ip = 0; ip < NIP; ++ip) {
      const float* p0 = P + (size_t)(b * NIP + ip) * NSPL * 512 + t;
#pragma unroll
      for (int il = 0; il < 4; ++il) {
        float sS = p0[il * 128] + p0[512 + il * 128]
                 + p0[1024 + il * 128] + p0[1536 + il * 128];
        m = fmaxf(m, 0.5f * sS + s_row[ip * 4 + il] + colt);
      }
    }
  }
#pragma unroll
  for (int off = 32; off; off >>= 1) m = fmaxf(m, __shfl_down(m, off, 64));
  if ((t & 63) == 0) s_mx[t >> 6] = m;
  __syncthreads();
  if (t == 0) out[b] = fmaxf(s_mx[0], s_mx[1]);
}

extern "C" void kernel_launch(void* const* d_in, const int* in_sizes, int n_in,
                              void* d_out, int out_size, void* d_ws, size_t ws_size,
                              hipStream_t stream) {
  // inputs: 0:x (unused), 1:z_tensor, 2:w_u, 3:b_u, 4:w_l, 5:b_l, 6:y_tensor
  const float* z  = (const float*)d_in[1];
  const float* wu = (const float*)d_in[2];
  const float* bu = (const float*)d_in[3];
  const float* wl = (const float*)d_in[4];
  const float* bl = (const float*)d_in[5];
  const float* y  = (const float*)d_in[6];
  float* P = (float*)d_ws;   // 3200 * 512 floats = 6.55 MB

  adv_main<<<NGRID, NT, 0, stream>>>(z, wu, wl, P);
  adv_fin<<<BATCH, 128, 0, stream>>>(P, bu, bl, y, (float*)d_out);
}